// Round 5
// baseline (336.659 us; speedup 1.0000x reference)
//
#include <hip/hip_runtime.h>
#include <math.h>

#define N_NODES 100000
#define N_EDGES 1600000
#define D_IN 128
#define HIDDEN 128
#define D_OUT 40
#define EPSN 1e-12f

// bucket = dst >> 8 (256 nodes per bucket)
#define NBUCK 391                            // ceil(100000/256)
#define EPB 4096                             // edges per bhist block
#define NPART ((N_EDGES + EPB - 1) / EPB)    // 391
#define PEPB 16384                           // edges per bpart block (long write runs)
#define PNPART ((N_EDGES + PEPB - 1) / PEPB) // 98

typedef __attribute__((ext_vector_type(8))) short short8;
typedef __attribute__((ext_vector_type(4))) float float4v;

static __device__ inline unsigned short f2bf(float f) {
    union { float f; unsigned u; } v; v.f = f;
    unsigned r = v.u + 0x7fffu + ((v.u >> 16) & 1u);
    return (unsigned short)(r >> 16);
}
static __device__ inline float bf2f(unsigned b) {
    union { unsigned u; float f; } v; v.u = b << 16;
    return v.f;
}

// ---------------- bucket histogram (LDS-staged) ----------------
__global__ void bhist_kernel(const int* __restrict__ dst, int* __restrict__ bucketCount) {
    __shared__ int h[NBUCK];
    for (int i = threadIdx.x; i < NBUCK; i += 256) h[i] = 0;
    __syncthreads();
    int es = blockIdx.x * EPB;
    int ee = min(es + EPB, N_EDGES);
    for (int i = es + threadIdx.x; i < ee; i += 256) atomicAdd(&h[dst[i] >> 8], 1);
    __syncthreads();
    for (int i = threadIdx.x; i < NBUCK; i += 256)
        if (h[i]) atomicAdd(&bucketCount[i], h[i]);
}

// ---------------- scan 391 bucket counts (one block) ----------------
__global__ void bscan_kernel(const int* __restrict__ bc, int* __restrict__ bstart,
                             int* __restrict__ cursor) {
    __shared__ int s[256];
    int t = threadIdx.x;
    int a = (2 * t < NBUCK) ? bc[2 * t] : 0;
    int b = (2 * t + 1 < NBUCK) ? bc[2 * t + 1] : 0;
    int tp = a + b;
    s[t] = tp;
    __syncthreads();
    for (int off = 1; off < 256; off <<= 1) {
        int tmp = (t >= off) ? s[t - off] : 0;
        __syncthreads();
        s[t] += tmp;
        __syncthreads();
    }
    int texcl = s[t] - tp;
    if (2 * t < NBUCK) { bstart[2 * t] = texcl; cursor[2 * t] = texcl; }
    if (2 * t + 1 < NBUCK) { bstart[2 * t + 1] = texcl + a; cursor[2 * t + 1] = texcl + a; }
    if (t == 255) bstart[NBUCK] = s[255];
}

// ---------------- partition edges into buckets (packed u32), long runs ----------------
__global__ __launch_bounds__(512) void bpart_kernel(
    const int* __restrict__ src, const int* __restrict__ dst,
    int* __restrict__ cursor, unsigned* __restrict__ pairs) {
    __shared__ int h[NBUCK];
    __shared__ int base[NBUCK];
    int t = threadIdx.x;
    for (int i = t; i < NBUCK; i += 512) h[i] = 0;
    __syncthreads();
    int es = blockIdx.x * PEPB;
    int ee = min(es + PEPB, N_EDGES);
    for (int i = es + t; i < ee; i += 512) atomicAdd(&h[dst[i] >> 8], 1);
    __syncthreads();
    for (int i = t; i < NBUCK; i += 512) {
        int c = h[i];
        base[i] = c ? atomicAdd(&cursor[i], c) : 0;
    }
    __syncthreads();
    for (int i = t; i < NBUCK; i += 512) h[i] = 0;
    __syncthreads();
    for (int i = es + t; i < ee; i += 512) {
        int d = dst[i];
        int bk = d >> 8;
        int r = atomicAdd(&h[bk], 1);
        pairs[base[bk] + r] = ((unsigned)src[i] << 8) | (unsigned)(d & 255);
    }
}

// ---------------- per-bucket CSR finalize: count+scan+fill all in LDS ----------------
__global__ void csr_kernel(const unsigned* __restrict__ pairs, const int* __restrict__ bstart,
                           int* __restrict__ hist, int* __restrict__ rowStart,
                           int* __restrict__ sortedSrc) {
    __shared__ int cnt[256];
    __shared__ int sc[256];
    __shared__ int cur[256];
    int b = blockIdx.x, t = threadIdx.x;
    int es = bstart[b], ee = bstart[b + 1];
    cnt[t] = 0;
    __syncthreads();
    for (int i = es + t; i < ee; i += 256) atomicAdd(&cnt[pairs[i] & 255], 1);
    __syncthreads();
    int v = cnt[t];
    sc[t] = v;
    __syncthreads();
    for (int off = 1; off < 256; off <<= 1) {
        int tmp = (t >= off) ? sc[t - off] : 0;
        __syncthreads();
        sc[t] += tmp;
        __syncthreads();
    }
    int excl = sc[t] - v;
    int node = (b << 8) + t;
    if (node < N_NODES) {
        hist[node] = v;
        rowStart[node] = es + excl;
    }
    cur[t] = excl;
    __syncthreads();
    for (int i = es + t; i < ee; i += 256) {
        unsigned p = pairs[i];
        int r = atomicAdd(&cur[p & 255], 1);
        sortedSrc[es + r] = (int)(p >> 8);
    }
}

// ---------------- precision / layout prep ----------------
__global__ void cast_kernel(const float* __restrict__ x, unsigned* __restrict__ xb) {
    int tid = blockIdx.x * blockDim.x + threadIdx.x;
    if (tid < N_NODES * 64) {
        float a = x[2 * tid], b = x[2 * tid + 1];
        xb[tid] = (unsigned)f2bf(a) | ((unsigned)f2bf(b) << 16);
    }
}

// Both weight swizzles in one launch. Layout:
// out[((kt*NC + c)*4 + quad)*16*8 + l15*8 + j] = W_cat[kt*32+quad*8+j][c*16+l15]
#define SWZ1_TOTAL (8 * 8 * 4 * 16 * 8)   // 32768
#define SWZ2_TOTAL (8 * 3 * 4 * 16 * 8)   // 12288
__global__ void swz_kernel(const float* __restrict__ Wl1, const float* __restrict__ Wr1,
                           const float* __restrict__ Wl2, const float* __restrict__ Wr2,
                           unsigned short* __restrict__ out1, unsigned short* __restrict__ out2) {
    int idx = blockIdx.x * blockDim.x + threadIdx.x;
    const float* Wl; const float* Wr; unsigned short* out; int NC, NOUT;
    if (idx < SWZ1_TOTAL) {
        Wl = Wl1; Wr = Wr1; out = out1; NC = 8; NOUT = HIDDEN;
    } else if (idx < SWZ1_TOTAL + SWZ2_TOTAL) {
        idx -= SWZ1_TOTAL;
        Wl = Wl2; Wr = Wr2; out = out2; NC = 3; NOUT = D_OUT;
    } else return;
    int j = idx & 7, l15 = (idx >> 3) & 15, quad = (idx >> 7) & 3;
    int rem = idx >> 9;
    int c = rem % NC, kt = rem / NC;
    int k = kt * 32 + quad * 8 + j;
    int n = c * 16 + l15;
    float val = 0.0f;
    if (n < NOUT) val = (k < 128) ? Wl[k * NOUT + n] : Wr[(k - 128) * NOUT + n];
    out[idx] = f2bf(val);
}

// ---------------- gather-mean: one wave per node, dwordx4, 8 edges/iter ----------------
__global__ void agg_kernel(const uint4* __restrict__ feat,  // [N][16] uint4 (8 bf16)
                           const int* __restrict__ sortedSrc,
                           const int* __restrict__ rowStart, const int* __restrict__ hist,
                           uint4* __restrict__ meanb) {
    int w = __builtin_amdgcn_readfirstlane((int)(threadIdx.x >> 6));
    int node = blockIdx.x * 4 + w;
    int lane = threadIdx.x & 63;
    int q = lane >> 4, sl = lane & 15;   // quarter 0..3 handles edge i+q
    int s0 = __builtin_amdgcn_readfirstlane(rowStart[node]);
    int cnt = __builtin_amdgcn_readfirstlane(hist[node]);
    float a0 = 0.f, a1 = 0.f, a2 = 0.f, a3 = 0.f, a4 = 0.f, a5 = 0.f, a6 = 0.f, a7 = 0.f;
    int i = 0;
    for (; i + 8 <= cnt; i += 8) {
        int sA = sortedSrc[s0 + i + q];
        int sB = sortedSrc[s0 + i + 4 + q];
        uint4 vA = feat[(size_t)sA * 16 + sl];
        uint4 vB = feat[(size_t)sB * 16 + sl];
        a0 += bf2f(vA.x & 0xffffu) + bf2f(vB.x & 0xffffu);
        a1 += bf2f(vA.x >> 16)     + bf2f(vB.x >> 16);
        a2 += bf2f(vA.y & 0xffffu) + bf2f(vB.y & 0xffffu);
        a3 += bf2f(vA.y >> 16)     + bf2f(vB.y >> 16);
        a4 += bf2f(vA.z & 0xffffu) + bf2f(vB.z & 0xffffu);
        a5 += bf2f(vA.z >> 16)     + bf2f(vB.z >> 16);
        a6 += bf2f(vA.w & 0xffffu) + bf2f(vB.w & 0xffffu);
        a7 += bf2f(vA.w >> 16)     + bf2f(vB.w >> 16);
    }
    for (; i + 4 <= cnt; i += 4) {
        int s = sortedSrc[s0 + i + q];
        uint4 v = feat[(size_t)s * 16 + sl];
        a0 += bf2f(v.x & 0xffffu); a1 += bf2f(v.x >> 16);
        a2 += bf2f(v.y & 0xffffu); a3 += bf2f(v.y >> 16);
        a4 += bf2f(v.z & 0xffffu); a5 += bf2f(v.z >> 16);
        a6 += bf2f(v.w & 0xffffu); a7 += bf2f(v.w >> 16);
    }
    int rem = cnt - i;  // 0..3
    if (q < rem) {
        int s = sortedSrc[s0 + i + q];
        uint4 v = feat[(size_t)s * 16 + sl];
        a0 += bf2f(v.x & 0xffffu); a1 += bf2f(v.x >> 16);
        a2 += bf2f(v.y & 0xffffu); a3 += bf2f(v.y >> 16);
        a4 += bf2f(v.z & 0xffffu); a5 += bf2f(v.z >> 16);
        a6 += bf2f(v.w & 0xffffu); a7 += bf2f(v.w >> 16);
    }
    // reduce across the 4 quarters
    a0 += __shfl_xor(a0, 16, 64); a0 += __shfl_xor(a0, 32, 64);
    a1 += __shfl_xor(a1, 16, 64); a1 += __shfl_xor(a1, 32, 64);
    a2 += __shfl_xor(a2, 16, 64); a2 += __shfl_xor(a2, 32, 64);
    a3 += __shfl_xor(a3, 16, 64); a3 += __shfl_xor(a3, 32, 64);
    a4 += __shfl_xor(a4, 16, 64); a4 += __shfl_xor(a4, 32, 64);
    a5 += __shfl_xor(a5, 16, 64); a5 += __shfl_xor(a5, 32, 64);
    a6 += __shfl_xor(a6, 16, 64); a6 += __shfl_xor(a6, 32, 64);
    a7 += __shfl_xor(a7, 16, 64); a7 += __shfl_xor(a7, 32, 64);
    if (q == 0) {
        float dinv = 1.0f / fmaxf((float)cnt, 1.0f);
        uint4 o;
        o.x = (unsigned)f2bf(a0 * dinv) | ((unsigned)f2bf(a1 * dinv) << 16);
        o.y = (unsigned)f2bf(a2 * dinv) | ((unsigned)f2bf(a3 * dinv) << 16);
        o.z = (unsigned)f2bf(a4 * dinv) | ((unsigned)f2bf(a5 * dinv) << 16);
        o.w = (unsigned)f2bf(a6 * dinv) | ((unsigned)f2bf(a7 * dinv) << 16);
        meanb[(size_t)node * 16 + sl] = o;
    }
}

// ---------------- layer 1 GEMM + L2norm + relu (MFMA) ----------------
__global__ __launch_bounds__(256) void gemm1_kernel(
    const unsigned short* __restrict__ meanb, const unsigned short* __restrict__ xb,
    const short* __restrict__ bswz, const float* __restrict__ bias,
    unsigned short* __restrict__ hb) {
    int w = __builtin_amdgcn_readfirstlane((int)(threadIdx.x >> 6));
    int lane = threadIdx.x & 63;
    int l15 = lane & 15, quad = lane >> 4;
    int n0 = blockIdx.x * 64;
    int nodeA = n0 + w * 16 + l15;
    if (nodeA >= N_NODES) nodeA = N_NODES - 1;

    float4v acc[8];
#pragma unroll
    for (int c = 0; c < 8; c++) acc[c] = (float4v){0.f, 0.f, 0.f, 0.f};

#pragma unroll
    for (int kt = 0; kt < 8; kt++) {
        const unsigned short* ab = (kt < 4) ? meanb : xb;
        int koff = (kt & 3) * 32 + quad * 8;
        short8 a = *(const short8*)(ab + (size_t)nodeA * 128 + koff);
#pragma unroll
        for (int c = 0; c < 8; c++) {
            short8 b = *(const short8*)(bswz + (((kt * 8 + c) * 4 + quad) * 16 + l15) * 8);
            acc[c] = __builtin_amdgcn_mfma_f32_16x16x32_bf16(a, b, acc[c], 0, 0, 0);
        }
    }

    float v[8][4];
    float ss[4] = {0.f, 0.f, 0.f, 0.f};
#pragma unroll
    for (int c = 0; c < 8; c++) {
        float bi = bias[c * 16 + l15];
#pragma unroll
        for (int r = 0; r < 4; r++) {
            float t = acc[c][r] + bi;
            v[c][r] = t;
            ss[r] += t * t;
        }
    }
#pragma unroll
    for (int r = 0; r < 4; r++)
        for (int off = 1; off < 16; off <<= 1) ss[r] += __shfl_xor(ss[r], off, 64);
#pragma unroll
    for (int r = 0; r < 4; r++) {
        int node = n0 + w * 16 + quad * 4 + r;
        if (node < N_NODES) {
            float inv = 1.0f / fmaxf(sqrtf(ss[r]), EPSN);
#pragma unroll
            for (int c = 0; c < 8; c++) {
                hb[(size_t)node * 128 + c * 16 + l15] = f2bf(fmaxf(v[c][r] * inv, 0.0f));
            }
        }
    }
}

// ---------------- layer 2 GEMM + L2norm + log_softmax (MFMA) ----------------
__global__ __launch_bounds__(256) void gemm2_kernel(
    const unsigned short* __restrict__ meanb, const unsigned short* __restrict__ hb,
    const short* __restrict__ bswz, const float* __restrict__ bias,
    float* __restrict__ out) {
    int w = __builtin_amdgcn_readfirstlane((int)(threadIdx.x >> 6));
    int lane = threadIdx.x & 63;
    int l15 = lane & 15, quad = lane >> 4;
    int n0 = blockIdx.x * 64;
    int nodeA = n0 + w * 16 + l15;
    if (nodeA >= N_NODES) nodeA = N_NODES - 1;

    float4v acc[3];
#pragma unroll
    for (int c = 0; c < 3; c++) acc[c] = (float4v){0.f, 0.f, 0.f, 0.f};

#pragma unroll
    for (int kt = 0; kt < 8; kt++) {
        const unsigned short* ab = (kt < 4) ? meanb : hb;
        int koff = (kt & 3) * 32 + quad * 8;
        short8 a = *(const short8*)(ab + (size_t)nodeA * 128 + koff);
#pragma unroll
        for (int c = 0; c < 3; c++) {
            short8 b = *(const short8*)(bswz + (((kt * 3 + c) * 4 + quad) * 16 + l15) * 8);
            acc[c] = __builtin_amdgcn_mfma_f32_16x16x32_bf16(a, b, acc[c], 0, 0, 0);
        }
    }

    float v[3][4];
    float ss[4] = {0.f, 0.f, 0.f, 0.f};
#pragma unroll
    for (int c = 0; c < 3; c++) {
        int col = c * 16 + l15;
        float bi = (col < D_OUT) ? bias[col] : 0.0f;
#pragma unroll
        for (int r = 0; r < 4; r++) {
            float t = acc[c][r] + bi;
            v[c][r] = t;
            ss[r] += t * t;
        }
    }
#pragma unroll
    for (int r = 0; r < 4; r++)
        for (int off = 1; off < 16; off <<= 1) ss[r] += __shfl_xor(ss[r], off, 64);

#pragma unroll
    for (int r = 0; r < 4; r++) {
        int node = n0 + w * 16 + quad * 4 + r;
        float inv = 1.0f / fmaxf(sqrtf(ss[r]), EPSN);
        float vn[3];
        float m = -INFINITY;
#pragma unroll
        for (int c = 0; c < 3; c++) {
            int col = c * 16 + l15;
            vn[c] = v[c][r] * inv;
            if (col < D_OUT) m = fmaxf(m, vn[c]);
        }
        for (int off = 1; off < 16; off <<= 1) m = fmaxf(m, __shfl_xor(m, off, 64));
        float se = 0.0f;
#pragma unroll
        for (int c = 0; c < 3; c++) {
            int col = c * 16 + l15;
            if (col < D_OUT) se += expf(vn[c] - m);
        }
        for (int off = 1; off < 16; off <<= 1) se += __shfl_xor(se, off, 64);
        float ls = logf(se);
        if (node < N_NODES) {
#pragma unroll
            for (int c = 0; c < 3; c++) {
                int col = c * 16 + l15;
                if (col < D_OUT) out[(size_t)node * D_OUT + col] = vn[c] - m - ls;
            }
        }
    }
}

static inline size_t align256(size_t x) { return (x + 255) & ~(size_t)255; }

extern "C" void kernel_launch(void* const* d_in, const int* in_sizes, int n_in,
                              void* d_out, int out_size, void* d_ws, size_t ws_size,
                              hipStream_t stream) {
    const float* x   = (const float*)d_in[0];
    const int*   ei  = (const int*)d_in[1];
    const float* Wl1 = (const float*)d_in[2];
    const float* bl1 = (const float*)d_in[3];
    const float* Wr1 = (const float*)d_in[4];
    const float* Wl2 = (const float*)d_in[5];
    const float* bl2 = (const float*)d_in[6];
    const float* Wr2 = (const float*)d_in[7];
    float* out = (float*)d_out;

    const int* src = ei;
    const int* dst = ei + N_EDGES;

    char* ws = (char*)d_ws;
    size_t off = 0;
    int* bucketCount = (int*)(ws + off); off += align256((size_t)NBUCK * 4);
    int* bucketStart = (int*)(ws + off); off += align256((size_t)(NBUCK + 1) * 4);
    int* cursor      = (int*)(ws + off); off += align256((size_t)NBUCK * 4);
    int* hist        = (int*)(ws + off); off += align256((size_t)N_NODES * 4);
    int* rowStart    = (int*)(ws + off); off += align256((size_t)N_NODES * 4);
    unsigned* pairs  = (unsigned*)(ws + off); off += align256((size_t)N_EDGES * 4);
    int* sortedSrc   = (int*)(ws + off); off += align256((size_t)N_EDGES * 4);
    unsigned* xb     = (unsigned*)(ws + off); off += align256((size_t)N_NODES * 128 * 2);
    unsigned* meanb  = (unsigned*)(ws + off); off += align256((size_t)N_NODES * 128 * 2);
    unsigned* hb     = (unsigned*)(ws + off); off += align256((size_t)N_NODES * 128 * 2);
    unsigned short* bswz1 = (unsigned short*)(ws + off); off += align256((size_t)SWZ1_TOTAL * 2);
    unsigned short* bswz2 = (unsigned short*)(ws + off); off += align256((size_t)SWZ2_TOTAL * 2);

    hipMemsetAsync(bucketCount, 0, (size_t)NBUCK * 4, stream);

    bhist_kernel<<<NPART, 256, 0, stream>>>(dst, bucketCount);
    bscan_kernel<<<1, 256, 0, stream>>>(bucketCount, bucketStart, cursor);
    bpart_kernel<<<PNPART, 512, 0, stream>>>(src, dst, cursor, pairs);
    csr_kernel<<<NBUCK, 256, 0, stream>>>(pairs, bucketStart, hist, rowStart, sortedSrc);

    cast_kernel<<<(N_NODES * 64 + 255) / 256, 256, 0, stream>>>(x, xb);
    swz_kernel<<<(SWZ1_TOTAL + SWZ2_TOTAL + 255) / 256, 256, 0, stream>>>(
        Wl1, Wr1, Wl2, Wr2, bswz1, bswz2);

    // layer 1
    agg_kernel<<<N_NODES / 4, 256, 0, stream>>>((const uint4*)xb, sortedSrc, rowStart, hist,
                                                (uint4*)meanb);
    gemm1_kernel<<<(N_NODES + 63) / 64, 256, 0, stream>>>(
        (const unsigned short*)meanb, (const unsigned short*)xb, (const short*)bswz1, bl1,
        (unsigned short*)hb);

    // layer 2
    agg_kernel<<<N_NODES / 4, 256, 0, stream>>>((const uint4*)hb, sortedSrc, rowStart, hist,
                                                (uint4*)meanb);
    gemm2_kernel<<<(N_NODES + 63) / 64, 256, 0, stream>>>(
        (const unsigned short*)meanb, (const unsigned short*)hb, (const short*)bswz2, bl2, out);
}